// Round 14
// baseline (235.992 us; speedup 1.0000x reference)
//
#include <hip/hip_runtime.h>
#include <hip/hip_bf16.h>
#include <math.h>

// Shapes: grd (N=64,C=64,24,24), sat (M=64,C=64,64,64); crop sat[:,:,12:52,12:52] (40x40)
// corr (64,64,17,17); out: [0,4096) similarity f32, [4096,40960) sat_f (64,24,24) f32.
//
// Round-14: corr_mfma restructured P3N1 -> P3N2 (each A-frag LDS read feeds 2 MFMAs;
// LDS reads/MFMA 1.33 -> 0.83) after round-13 counters showed pure LDS-pipe bound
// (traffic 92.6us + conflicts 40us = 133 ~ wall 136.5; MFMA 47us hidden).
// Single bf16-product corr (sigma~0.5 vs corr sigma~192: only near-ties flip; sim
// error <2e-4 << 0.085); (63,63) argmax exact via fp32 rescore for sat_f.
// S2 (patch-norm partials) fused into make_satT; gn2 fused into make_grdT.

typedef float f32x16 __attribute__((ext_vector_type(16)));
typedef short short8 __attribute__((ext_vector_type(8)));

// ws layout (float words)
#define SATT_H 0u          // bf16 [m][1600 pix][64 c] = 3,276,800 f
#define GRDT_H 3276800u    // bf16 [ij=576][n=64][c=64] = 1,179,648 f
#define CORR_O 4456448u    // f32 [m][304][64] = 1,245,184 f
#define WIN2_O 5701632u    // f32 [m][289] -> 18,496 f
#define GN2_O  5720128u    // f32 [64]
#define IDX_O  5720192u    // int [4096] (1024 f)
#define CEX_O  5721216u    // f32 [289] -> pad to 384
#define S2G_O  5721600u    // f32 [m][1600] = 102,400 f

// Injective LDS address transform (same on write and read): XOR row bits (6,7,8)
// into chunk bits (4,5,6); spreads 64-B-strided row reads across bank groups.
#define SWZ64(off) ((off) ^ ((((off) >> 6) & 7) << 4))

// ---------- T1: satT bf16 channel-last + S2 row partials. grid 2560 = (m,r) ----------
__global__ __launch_bounds__(256) void make_satT(const float* __restrict__ sat,
                                                 __hip_bfloat16* __restrict__ sth,
                                                 float* __restrict__ S2g) {
    __shared__ __hip_bfloat16 th[40 * 66];
    __shared__ float s2[40];
    int m = blockIdx.x / 40, r = blockIdx.x % 40;
    int tid = threadIdx.x;
    if (tid < 40) s2[tid] = 0.0f;
    __syncthreads();
    const float* base = sat + (size_t)m * 262144 + (12 + r) * 64 + 12;
    for (int k = 0; k < 10; k++) {
        int idx = tid + 256 * k;          // 2560 = 64c * 40w
        int c = idx / 40, w2 = idx % 40;
        float v = base[c * 4096 + w2];
        th[w2 * 66 + c] = __float2bfloat16(v);
        atomicAdd(&s2[w2], v * v);
    }
    __syncthreads();
    __hip_bfloat16* dh = sth + (size_t)m * 102400 + r * 2560;
    for (int k = 0; k < 10; k++) {
        int idx = tid + 256 * k;          // idx = w*64 + c
        int w2 = idx >> 6, c = idx & 63;
        dh[idx] = th[w2 * 66 + c];
    }
    if (tid < 40) S2g[m * 1600 + r * 40 + tid] = s2[tid];
}

// ---------- T2: grdT bf16 [ij][n][c] + gn2 partial. grid 128 = (n, c-half) ----------
__global__ __launch_bounds__(256) void make_grdT(const float* __restrict__ grd,
                                                 __hip_bfloat16* __restrict__ gth,
                                                 float* __restrict__ gn2) {
    __shared__ __hip_bfloat16 t[32 * 577];
    __shared__ float red[4];
    int bid = blockIdx.x;
    int n = bid >> 1, ch = bid & 1;
    int tid = threadIdx.x;
    const float* src = grd + (size_t)n * 36864 + ch * 32 * 576;
    float s = 0.0f;
    for (int k = 0; k < 72; k++) {
        int idx = tid + 256 * k;          // idx = cl*576 + ij
        int cl = idx / 576, ij = idx % 576;
        float v = src[idx];
        s += v * v;
        t[cl * 577 + ij] = __float2bfloat16(v);
    }
    for (int off = 32; off; off >>= 1) s += __shfl_down(s, off);
    if ((tid & 63) == 0) red[tid >> 6] = s;
    __syncthreads();
    if (tid == 0) atomicAdd(&gn2[n], red[0] + red[1] + red[2] + red[3]);
    for (int k = 0; k < 72; k++) {
        int idx = tid + 256 * k;          // idx = ij*32 + cl
        int ij = idx >> 5, cl = idx & 31;
        gth[(size_t)ij * 4096 + n * 64 + ch * 32 + cl] = t[cl * 577 + ij];
    }
}

// ---------- N1: window norms^2 from S2 partials (separable). grid 64 (m) ----------
__global__ __launch_bounds__(256) void make_win2(const float* __restrict__ S2g,
                                                 float* __restrict__ win2) {
    __shared__ float S2[40][41];
    __shared__ float RS[40][18];
    int m = blockIdx.x, tid = threadIdx.x;
    for (int k = 0; k < 7; k++) {
        int idx = tid + 256 * k;
        if (idx < 1600) S2[idx / 40][idx % 40] = S2g[m * 1600 + idx];
    }
    __syncthreads();
    for (int k = 0; k < 3; k++) {
        int idx = tid + 256 * k;
        if (idx < 680) {
            int r = idx / 17, x = idx % 17;
            float s = 0.0f;
            for (int j = 0; j < 24; j++) s += S2[r][x + j];
            RS[r][x] = s;
        }
    }
    __syncthreads();
    for (int k = 0; k < 2; k++) {
        int idx = tid + 256 * k;
        if (idx < 289) {
            int y = idx / 17, x = idx % 17;
            float s = 0.0f;
            for (int i2 = 0; i2 < 24; i2++) s += RS[y + i2][x];
            win2[m * 289 + idx] = s;
        }
    }
}

// ---------- K1: MFMA corr (32x32x16, P3N2). grid 512; block 256 = 4 waves ----------
// p: 289 -> 12 tiles of 32 (loads clamp to p=288, stores guarded). Wave w (0..3):
// p-tiles {w, w+4, w+8}, BOTH n-tiles. Per (cc,ijl): per ks, 2 B-frag + 3 A-frag
// LDS reads feed 6 MFMA (ratio 10/12 vs round-13's 8/6 -> LDS traffic x0.625).
// acc = 6 x f32x16 = 96 AGPR. Bl double-buffered, vnext 2-deep reg prefetch
// issued at top of iter so the end-of-iter barrier's vmcnt drain is ~complete.
__global__ __launch_bounds__(256, 2) void corr_mfma(const __hip_bfloat16* __restrict__ sth,
                                                    const __hip_bfloat16* __restrict__ gth,
                                                    float* __restrict__ corr) {
    __shared__ __align__(16) __hip_bfloat16 satW[760 * 32];   // 48,640 B
    __shared__ __align__(16) __hip_bfloat16 Bl[2][64 * 32];   // 2 x 4,096 B

    int bid = blockIdx.x;
    int xcd = bid & 7, slot = bid >> 3;            // XCD-aware: 8 m per XCD
    int m = xcd * 8 + (slot >> 3), iq = slot & 7;  // iq = i-slice (3 rows)
    int tid = threadIdx.x;
    int w = tid >> 6, l = tid & 63;
    int ln31 = l & 31, h = l >> 5;

    int rowbase[3];
#pragma unroll
    for (int t = 0; t < 3; t++) {
        int p = (w + 4 * t) * 32 + ln31;
        if (p > 288) p = 288;                      // ghost rows read a valid pixel
        rowbase[t] = (p / 17) * 40 + (p % 17);
    }
    f32x16 acc[3][2];
#pragma unroll
    for (int t = 0; t < 3; t++) {
        acc[t][0] = (f32x16)0.0f;
        acc[t][1] = (f32x16)0.0f;
    }

    const __hip_bfloat16* satb = sth + (size_t)m * 102400 + iq * 7680;
    size_t gb = (size_t)(iq * 72) * 4096 + (tid >> 2) * 64 + (tid & 3) * 8;
    int bdst = SWZ64(tid * 16);
    int bro[2][2];
#pragma unroll
    for (int nt = 0; nt < 2; nt++)
#pragma unroll
        for (int ks = 0; ks < 2; ks++)
            bro[nt][ks] = SWZ64((nt * 32 + ln31) * 64 + ks * 32 + h * 16);

#pragma unroll
    for (int cc = 0; cc < 2; cc++) {
        __syncthreads();                           // prior satW/Bl reads done
        // stage satW for this c-chunk: 3040 16-B slots
#pragma unroll
        for (int k2 = 0; k2 < 12; k2++) {
            int idx = tid + 256 * k2;
            if (idx < 3040) {
                float4 v = *(const float4*)(satb + (idx >> 2) * 64 + cc * 32 + (idx & 3) * 8);
                *(float4*)((char*)satW + SWZ64(idx * 16)) = v;
            }
        }
        float4 vnext;
        {
            float4 v0 = *(const float4*)(gth + gb + cc * 32);                 // ij 0
            *(float4*)((char*)&Bl[0][0] + bdst) = v0;
            vnext = *(const float4*)(gth + gb + 4096 + cc * 32);              // ij 1
        }
        __syncthreads();

        for (int ijl = 0; ijl < 72; ijl++) {
            int buf = ijl & 1;
            if (ijl + 1 < 72) {
                *(float4*)((char*)&Bl[buf ^ 1][0] + bdst) = vnext;            // data(ij+1)
                if (ijl + 2 < 72)
                    vnext = *(const float4*)(gth + gb + (size_t)(ijl + 2) * 4096 + cc * 32);
            }
            int pixoff = (ijl / 24) * 40 + (ijl % 24);
#pragma unroll
            for (int ks = 0; ks < 2; ks++) {
                short8 bf0 = *(const short8*)((const char*)&Bl[buf][0] + bro[0][ks]);
                short8 bf1 = *(const short8*)((const char*)&Bl[buf][0] + bro[1][ks]);
#pragma unroll
                for (int t = 0; t < 3; t++) {
                    int pix = rowbase[t] + pixoff;
                    int ao = pix * 64 + ks * 32 + h * 16;
                    short8 af = *(const short8*)((const char*)satW + (ao ^ ((pix & 7) << 4)));
                    acc[t][0] = __builtin_amdgcn_mfma_f32_32x32x16_bf16(af, bf0, acc[t][0], 0, 0, 0);
                    acc[t][1] = __builtin_amdgcn_mfma_f32_32x32x16_bf16(af, bf1, acc[t][1], 0, 0, 0);
                }
            }
            __syncthreads();
        }
    }

#pragma unroll
    for (int t = 0; t < 3; t++) {
        int tile = w + 4 * t;
#pragma unroll
        for (int nt = 0; nt < 2; nt++)
#pragma unroll
            for (int q = 0; q < 16; q++) {
                int prow = tile * 32 + (q & 3) + 8 * (q >> 2) + 4 * h;
                if (prow < 289)
                    atomicAdd(&corr[((size_t)m * 304 + prow) * 64 + nt * 32 + ln31],
                              acc[t][nt][q]);
            }
    }
}

// ---------- K2: argmax + similarity. grid 4096 = (m,n); block 64 ----------
__global__ __launch_bounds__(64) void argsim(const float* __restrict__ corr,
                                             const float* __restrict__ win2,
                                             const float* __restrict__ gn2,
                                             float* __restrict__ out,
                                             int* __restrict__ idxb) {
    int b = blockIdx.x, m = b >> 6, n = b & 63, lane = threadIdx.x;
    float bv = -3.0e38f;
    int bi = 1 << 30;
    for (int k = 0; k < 5; k++) {
        int p = lane + 64 * k;
        if (p < 289) {
            float v = corr[((size_t)m * 304 + p) * 64 + n];
            if (v > bv) { bv = v; bi = p; }   // ascending p: strict > = first occurrence
        }
    }
    for (int off = 32; off; off >>= 1) {
        float ov = __shfl_down(bv, off);
        int oi = __shfl_down(bi, off);
        if (ov > bv || (ov == bv && oi < bi)) { bv = ov; bi = oi; }
    }
    if (lane == 0) {
        float np = sqrtf(win2[m * 289 + bi]);
        float ng = sqrtf(gn2[n]);
        out[b] = bv / (fmaxf(np, 1e-12f) * fmaxf(ng, 1e-12f));
        idxb[b] = bi;
    }
}

// ---------- K3a: exact fp32 corr for (m,n)=(63,63). grid 289; block 256 ----------
__global__ __launch_bounds__(256) void exact63(const float* __restrict__ sat,
                                               const float* __restrict__ grd,
                                               float* __restrict__ correx) {
    int p = blockIdx.x;
    int hy = p / 17, wx = p % 17;
    int tid = threadIdx.x;
    const float* satm = sat + (size_t)63 * 262144;
    const float* grdn = grd + (size_t)63 * 36864;
    float dot = 0.0f;
    for (int e = tid; e < 36864; e += 256) {
        int c = e / 576, rem = e - c * 576;
        int i = rem / 24, j = rem - i * 24;
        dot += satm[c * 4096 + (12 + hy + i) * 64 + 12 + wx + j] * grdn[e];
    }
    for (int off = 32; off; off >>= 1) dot += __shfl_down(dot, off);
    __shared__ float red[4];
    if ((tid & 63) == 0) red[tid >> 6] = dot;
    __syncthreads();
    if (tid == 0) correx[p] = red[0] + red[1] + red[2] + red[3];
}

// ---------- K3b: fix (63,63) argmax + sim from exact values. grid 1; block 64 ----------
__global__ __launch_bounds__(64) void fix63(const float* __restrict__ correx,
                                            const float* __restrict__ win2,
                                            const float* __restrict__ gn2,
                                            float* __restrict__ out,
                                            int* __restrict__ idxb) {
    int lane = threadIdx.x;
    float bv = -3.0e38f;
    int bi = 1 << 30;
    for (int k = 0; k < 5; k++) {
        int p = lane + 64 * k;
        if (p < 289) {
            float v = correx[p];
            if (v > bv) { bv = v; bi = p; }
        }
    }
    for (int off = 32; off; off >>= 1) {
        float ov = __shfl_down(bv, off);
        int oi = __shfl_down(bi, off);
        if (ov > bv || (ov == bv && oi < bi)) { bv = ov; bi = oi; }
    }
    if (lane == 0) {
        out[4095] = bv / (fmaxf(sqrtf(win2[63 * 289 + bi]), 1e-12f) *
                          fmaxf(sqrtf(gn2[63]), 1e-12f));
        idxb[4095] = bi;
    }
}

// ---------- K4: winning patch for (63,63). grid 144; block 256 ----------
__global__ __launch_bounds__(256) void copy_patch(const float* __restrict__ sat,
                                                  const int* __restrict__ idxb,
                                                  float* __restrict__ out) {
    int fidx = idxb[4095];
    int hy = fidx / 17, wx = fidx % 17;
    int e = blockIdx.x * 256 + threadIdx.x;   // < 36864
    int c = e / 576;
    int rem = e - c * 576;
    int rr = rem / 24, col = rem - rr * 24;
    out[4096 + e] = sat[(size_t)(63 * 64 + c) * 4096 + (12 + hy + rr) * 64 + 12 + wx + col];
}

extern "C" void kernel_launch(void* const* d_in, const int* in_sizes, int n_in,
                              void* d_out, int out_size, void* d_ws, size_t ws_size,
                              hipStream_t stream) {
    const float* grd = (const float*)d_in[0];
    const float* sat = (const float*)d_in[1];
    float* out = (float*)d_out;

    float* wsf = (float*)d_ws;
    __hip_bfloat16* sth = (__hip_bfloat16*)(wsf + SATT_H);
    __hip_bfloat16* gth = (__hip_bfloat16*)(wsf + GRDT_H);
    float* corr = wsf + CORR_O;
    float* win2 = wsf + WIN2_O;
    float* gn2  = wsf + GN2_O;
    int*   idxb = (int*)(wsf + IDX_O);
    float* cex  = wsf + CEX_O;
    float* S2g  = wsf + S2G_O;

    // one memset covers corr + win2 + gn2 (contiguous): 1,263,744 floats
    hipMemsetAsync(corr, 0, (size_t)1263744 * sizeof(float), stream);
    make_satT<<<2560, 256, 0, stream>>>(sat, sth, S2g);
    make_grdT<<<128, 256, 0, stream>>>(grd, gth, gn2);
    make_win2<<<64, 256, 0, stream>>>(S2g, win2);
    corr_mfma<<<512, 256, 0, stream>>>(sth, gth, corr);
    argsim<<<4096, 64, 0, stream>>>(corr, win2, gn2, out, idxb);
    exact63<<<289, 256, 0, stream>>>(sat, grd, cex);
    fix63<<<1, 64, 0, stream>>>(cex, win2, gn2, out, idxb);
    copy_patch<<<144, 256, 0, stream>>>(sat, idxb, out);
}